// Round 1
// baseline (22869.659 us; speedup 1.0000x reference)
//
#include <hip/hip_runtime.h>
#include <stdint.h>
#include <math.h>

#define S_LEN 2048
#define HID   4096
#define NH    32
#define HD    128
#define KSEL  256

typedef unsigned short u16;
typedef __attribute__((ext_vector_type(8))) short short8;
typedef __attribute__((ext_vector_type(4))) float floatx4;

__device__ __forceinline__ float bf2f(u16 u){ return __uint_as_float(((unsigned)u) << 16); }
__device__ __forceinline__ u16 f2bf(float f){
  unsigned u = __float_as_uint(f);
  u += 0x7fffu + ((u >> 16) & 1u);   // RTNE
  return (u16)(u >> 16);
}
// monotonic float -> unsigned key (larger float -> larger key)
__device__ __forceinline__ unsigned okey(float x){
  unsigned b = __float_as_uint(x);
  return (b & 0x80000000u) ? ~b : (b | 0x80000000u);
}
__device__ __forceinline__ void async16(const void* g, void* l){
  __builtin_amdgcn_global_load_lds((const __attribute__((address_space(1))) unsigned int*)g,
                                   (__attribute__((address_space(3))) unsigned int*)l,
                                   16, 0, 0);
}
__device__ __forceinline__ float waveMax(float v){
  #pragma unroll
  for (int o = 32; o; o >>= 1) v = fmaxf(v, __shfl_down(v, o));
  return v;
}
__device__ __forceinline__ float waveSum(float v){
  #pragma unroll
  for (int o = 32; o; o >>= 1) v += __shfl_down(v, o);
  return v;
}

// ---------------- dtype detection ----------------
// If the buffer really holds bf16, even-index uint16s decode to sane magnitudes
// (~100%). If it holds fp32, even-index uint16s are mantissa low bits (~17% sane).
__global__ void detect_dtype(const u16* __restrict__ h, int* __restrict__ flag){
  int cnt = 0;
  for (int i = threadIdx.x; i < 256; i += 64) {
    float v = bf2f(h[2*i]);
    float a = fabsf(v);
    if (a >= 1e-12f && a <= 16.0f) cnt++;
  }
  #pragma unroll
  for (int o = 32; o; o >>= 1) cnt += __shfl_down(cnt, o);
  if (threadIdx.x == 0) *flag = (cnt >= 160) ? 1 : 0;
}

__global__ void sentinel_kernel(float* out){ out[0] = 12345.0f; }

// ---------------- convert to canonical bf16 ----------------
__global__ void to_bf16(const void* __restrict__ src, u16* __restrict__ dst,
                        int n8, const int* __restrict__ flag)
{
  int i = blockIdx.x * blockDim.x + threadIdx.x;
  if (i >= n8) return;
  if (*flag != 0) {
    ((uint4*)dst)[i] = ((const uint4*)src)[i];
  } else {
    const float4* s = (const float4*)src;
    float4 a = s[2*i], b = s[2*i+1];
    uint4 u;
    u.x = (unsigned)f2bf(a.x) | ((unsigned)f2bf(a.y) << 16);
    u.y = (unsigned)f2bf(a.z) | ((unsigned)f2bf(a.w) << 16);
    u.z = (unsigned)f2bf(b.x) | ((unsigned)f2bf(b.y) << 16);
    u.w = (unsigned)f2bf(b.z) | ((unsigned)f2bf(b.w) << 16);
    ((uint4*)dst)[i] = u;
  }
}

// ---------------- GEMM: C[M,N] = A[M,K] * B[N,K]^T (NT), bf16 in, fp32 acc ----
// m97 recipe: 128x128 tile, BK=64, 4 waves (2x2 of 64x64), global_load_lds w=16,
// XOR swizzle at 16B-chunk granularity so ds_read_b128 frag loads are 2-way only.
__global__ __launch_bounds__(256) void gemm_bt(const u16* __restrict__ A,
    const u16* __restrict__ B, void* __restrict__ C,
    int M, int N, int K, int out_mode, const int* __restrict__ flag)
{
  __shared__ u16 As[128*64];
  __shared__ u16 Bs[128*64];
  const int tid  = threadIdx.x;
  const int wave = tid >> 6;
  const int lane = tid & 63;
  const int quad = lane >> 4;
  const int l16  = lane & 15;
  const int wr = wave >> 1, wc = wave & 1;
  const int bm = blockIdx.y * 128;
  const int bn = blockIdx.x * 128;
  const int rsub = lane >> 3;   // 0..7 row within segment
  const int csub = lane & 7;    // 0..7 16B chunk

  floatx4 acc[4][4];
  #pragma unroll
  for (int i = 0; i < 4; i++)
    #pragma unroll
    for (int j = 0; j < 4; j++)
      #pragma unroll
      for (int r = 0; r < 4; r++) acc[i][j][r] = 0.0f;

  for (int k0 = 0; k0 < K; k0 += 64) {
    #pragma unroll
    for (int i = 0; i < 4; i++) {
      const int s = wave*4 + i;          // segment 0..15 (8 rows each)
      const int r = s*8 + rsub;          // tile row 0..127
      const int c = csub ^ (r & 7);      // swizzled 16B chunk
      const size_t goff = (size_t)r * K + (size_t)(k0 + c*8);
      async16(A + (size_t)bm * K + goff, &As[s*512]);
      async16(B + (size_t)bn * K + goff, &Bs[s*512]);
    }
    __syncthreads();
    #pragma unroll
    for (int ks = 0; ks < 2; ks++) {
      short8 fa[4], fb[4];
      #pragma unroll
      for (int mi = 0; mi < 4; mi++) {
        int m = wr*64 + mi*16 + l16;
        int phys = (ks*4 + quad) ^ (m & 7);
        fa[mi] = *(const short8*)&As[m*64 + phys*8];
      }
      #pragma unroll
      for (int ni = 0; ni < 4; ni++) {
        int n = wc*64 + ni*16 + l16;
        int phys = (ks*4 + quad) ^ (n & 7);
        fb[ni] = *(const short8*)&Bs[n*64 + phys*8];
      }
      #pragma unroll
      for (int mi = 0; mi < 4; mi++)
        #pragma unroll
        for (int ni = 0; ni < 4; ni++)
          acc[mi][ni] = __builtin_amdgcn_mfma_f32_16x16x32_bf16(fa[mi], fb[ni], acc[mi][ni], 0, 0, 0);
    }
    __syncthreads();
  }

  const bool outbf = (out_mode == 0) || (*flag != 0);
  #pragma unroll
  for (int mi = 0; mi < 4; mi++) {
    #pragma unroll
    for (int ni = 0; ni < 4; ni++) {
      #pragma unroll
      for (int r = 0; r < 4; r++) {
        int row = bm + wr*64 + mi*16 + quad*4 + r;   // C/D: row = quad*4+reg
        int col = bn + wc*64 + ni*16 + l16;          //       col = lane&15
        float v = acc[mi][ni][r];
        size_t idx = (size_t)row * N + col;
        if (outbf) ((u16*)C)[idx] = f2bf(v);
        else       ((float*)C)[idx] = v;
      }
    }
  }
}

// ---------------- RoPE in place on bf16 Q,K ----------------
__global__ void rope_kernel(u16* __restrict__ Q, u16* __restrict__ Kb,
                            const int* __restrict__ pos)
{
  int n = blockIdx.x * blockDim.x + threadIdx.x;  // S*NH*64
  if (n >= S_LEN * NH * 64) return;
  int s   = n >> 11;        // / (NH*64)
  int rem = n & 2047;
  int h = rem >> 6;
  int j = rem & 63;
  float p = (float)pos[s];
  float inv = expf(-(float)j * 0.14391156831212787f);  // ln(10000)/64
  float arg = p * inv;
  float c = cosf(arg), sn = sinf(arg);
  size_t base = (size_t)s * HID + (size_t)h * HD + j;
  float q1 = bf2f(Q[base]), q2 = bf2f(Q[base + 64]);
  Q[base]      = f2bf(q1 * c - q2 * sn);
  Q[base + 64] = f2bf(q2 * c + q1 * sn);
  float k1 = bf2f(Kb[base]), k2 = bf2f(Kb[base + 64]);
  Kb[base]      = f2bf(k1 * c - k2 * sn);
  Kb[base + 64] = f2bf(k2 * c + k1 * sn);
}

// ---------------- attention: one block per (q row, head) ----------------
__global__ __launch_bounds__(256) void attn_kernel(const u16* __restrict__ Q,
    const u16* __restrict__ Kb, const u16* __restrict__ V, u16* __restrict__ O)
{
  __shared__ float sc[S_LEN];
  __shared__ float qv[HD];
  __shared__ unsigned hist[256];
  __shared__ float redf[4];
  __shared__ unsigned bc[4];
  __shared__ float obuf[256];

  const int tid = threadIdx.x;
  const int q   = blockIdx.x;
  const int h   = blockIdx.y;
  const int valid = q + 1;

  if (tid < HD) qv[tid] = bf2f(Q[(size_t)q * HID + (size_t)h * HD + tid]);
  __syncthreads();

  // scores for j <= q
  for (int j = tid; j <= q; j += 256) {
    const uint4* kr = (const uint4*)(Kb + (size_t)j * HID + (size_t)h * HD);
    float acc = 0.f;
    #pragma unroll
    for (int c = 0; c < 16; c++) {
      uint4 u = kr[c];
      acc += qv[c*8+0] * __uint_as_float(u.x << 16)
           + qv[c*8+1] * __uint_as_float(u.x & 0xffff0000u)
           + qv[c*8+2] * __uint_as_float(u.y << 16)
           + qv[c*8+3] * __uint_as_float(u.y & 0xffff0000u)
           + qv[c*8+4] * __uint_as_float(u.z << 16)
           + qv[c*8+5] * __uint_as_float(u.z & 0xffff0000u)
           + qv[c*8+6] * __uint_as_float(u.w << 16)
           + qv[c*8+7] * __uint_as_float(u.w & 0xffff0000u);
    }
    sc[j] = acc * 0.08838834764831845f;   // 1/sqrt(128)
  }
  __syncthreads();

  // exact top-256 threshold via 4-pass radix select on ordered keys
  unsigned tkey = 0;
  const bool dosel = (valid > KSEL);
  if (dosel) {
    unsigned prefix = 0, r = KSEL;
    for (int shift = 24; shift >= 0; shift -= 8) {
      hist[tid] = 0;
      __syncthreads();
      for (int j = tid; j <= q; j += 256) {
        unsigned kk = okey(sc[j]);
        bool match = (shift == 24) || ((kk >> (shift + 8)) == prefix);
        if (match) atomicAdd(&hist[(kk >> shift) & 255], 1u);
      }
      __syncthreads();
      if (tid == 0) {
        unsigned a = 0;
        for (int d = 255; d >= 0; --d) {
          unsigned c = hist[d];
          if (a + c >= r) { bc[0] = (unsigned)d; bc[1] = r - a; bc[2] = c; break; }
          a += c;
        }
      }
      __syncthreads();
      prefix = (prefix << 8) | bc[0];
      r = bc[1];
    }
    tkey = prefix;
    const unsigned ceq = bc[2];   // count of keys == tkey
    const unsigned need = r;      // how many ties to keep (lowest index first)
    if (ceq != need) {            // block-uniform, rare
      if (tid == 0) {
        unsigned seen = 0;
        for (int j = 0; j <= q; j++) {
          if (okey(sc[j]) == tkey) {
            if (seen >= need) sc[j] = -INFINITY;  // deselect extra ties
            seen++;
          }
        }
      }
      __syncthreads();
    }
  }

  // max over valid (top-k always contains the max)
  float lm = -INFINITY;
  for (int j = tid; j <= q; j += 256) lm = fmaxf(lm, sc[j]);
  lm = waveMax(lm);
  if ((tid & 63) == 0) redf[tid >> 6] = lm;
  __syncthreads();
  const float mx = fmaxf(fmaxf(redf[0], redf[1]), fmaxf(redf[2], redf[3]));
  __syncthreads();   // protect redf reuse

  // weights (overwrite sc in place) + partial sums
  float lsum = 0.f;
  for (int j = tid; j <= q; j += 256) {
    float s = sc[j];
    float w = dosel ? ((okey(s) >= tkey) ? expf(s - mx) : 0.f) : expf(s - mx);
    sc[j] = w;
    lsum += w;
  }
  lsum = waveSum(lsum);
  if ((tid & 63) == 0) redf[tid >> 6] = lsum;
  __syncthreads();
  const float invs = 1.f / (redf[0] + redf[1] + redf[2] + redf[3]);

  // PV: 2 threads per output dim, strided over j
  const int d = tid & 127;
  const int half = tid >> 7;
  float acc = 0.f;
  for (int j = half; j <= q; j += 2) {
    float w = sc[j];
    if (w > 0.f) acc += w * bf2f(V[(size_t)j * HID + (size_t)h * HD + d]);
  }
  obuf[half * 128 + d] = acc;
  __syncthreads();
  if (tid < 128) {
    float o = (obuf[tid] + obuf[128 + tid]) * invs;
    O[(size_t)q * HID + (size_t)h * HD + tid] = f2bf(o);
  }
}

// ---------------- launch ----------------
extern "C" void kernel_launch(void* const* d_in, const int* in_sizes, int n_in,
                              void* d_out, int out_size, void* d_ws, size_t ws_size,
                              hipStream_t stream)
{
  (void)in_sizes; (void)n_in; (void)out_size;
  const void* hidden = d_in[0];
  const int*  pos    = (const int*)d_in[2];
  const void* Wq     = d_in[3];
  const void* Wk     = d_in[4];
  const void* Wv     = d_in[5];
  const void* Wo     = d_in[6];

  const size_t SH2 = (size_t)S_LEN * HID * 2;   // 16,777,216
  const size_t W2  = (size_t)HID * HID * 2;     // 33,554,432
  const size_t NEEDED = 256 + SH2 + W2 + 3 * SH2 + SH2;
  if (ws_size < NEEDED) {  // visible failure marker instead of OOB scribble
    sentinel_kernel<<<1, 1, 0, stream>>>((float*)d_out);
    return;
  }

  char* ws = (char*)d_ws;
  int* flag = (int*)ws;
  u16* hb = (u16*)(ws + 256);
  u16* wb = (u16*)(ws + 256 + SH2);
  u16* qb = (u16*)(ws + 256 + SH2 + W2);
  u16* kb = (u16*)(ws + 256 + SH2 + W2 + SH2);
  u16* vb = (u16*)(ws + 256 + SH2 + W2 + 2 * SH2);
  u16* ab = (u16*)(ws + 256 + SH2 + W2 + 3 * SH2);

  detect_dtype<<<1, 64, 0, stream>>>((const u16*)hidden, flag);

  const int nh8 = S_LEN * HID / 8;   // 1,048,576
  const int nw8 = HID * HID / 8;     // 2,097,152
  to_bf16<<<nh8 / 256, 256, 0, stream>>>(hidden, hb, nh8, flag);

  dim3 ggrid(HID / 128, S_LEN / 128);  // (32, 16)

  to_bf16<<<nw8 / 256, 256, 0, stream>>>(Wq, wb, nw8, flag);
  gemm_bt<<<ggrid, 256, 0, stream>>>(hb, wb, (void*)qb, S_LEN, HID, HID, 0, flag);

  to_bf16<<<nw8 / 256, 256, 0, stream>>>(Wk, wb, nw8, flag);
  gemm_bt<<<ggrid, 256, 0, stream>>>(hb, wb, (void*)kb, S_LEN, HID, HID, 0, flag);

  to_bf16<<<nw8 / 256, 256, 0, stream>>>(Wv, wb, nw8, flag);
  gemm_bt<<<ggrid, 256, 0, stream>>>(hb, wb, (void*)vb, S_LEN, HID, HID, 0, flag);

  rope_kernel<<<(S_LEN * NH * 64) / 256, 256, 0, stream>>>(qb, kb, pos);

  attn_kernel<<<dim3(S_LEN, NH), 256, 0, stream>>>(qb, kb, vb, ab);

  to_bf16<<<nw8 / 256, 256, 0, stream>>>(Wo, wb, nw8, flag);
  gemm_bt<<<ggrid, 256, 0, stream>>>(ab, wb, d_out, S_LEN, HID, HID, 1, flag);
}

// Round 2
// 2462.894 us; speedup vs baseline: 9.2857x; 9.2857x over previous
//
#include <hip/hip_runtime.h>
#include <stdint.h>
#include <math.h>

#define S_LEN 2048
#define HID   4096
#define NH    32
#define HD    128
#define KSEL  256

typedef unsigned short u16;
typedef __attribute__((ext_vector_type(8))) short short8;
typedef __attribute__((ext_vector_type(4))) float floatx4;

__device__ __forceinline__ float bf2f(u16 u){ return __uint_as_float(((unsigned)u) << 16); }
__device__ __forceinline__ u16 f2bf(float f){
  unsigned u = __float_as_uint(f);
  u += 0x7fffu + ((u >> 16) & 1u);   // RTNE
  return (u16)(u >> 16);
}
// monotonic float -> unsigned key (larger float -> larger key)
__device__ __forceinline__ unsigned okey(float x){
  unsigned b = __float_as_uint(x);
  return (b & 0x80000000u) ? ~b : (b | 0x80000000u);
}
__device__ __forceinline__ void async16(const void* g, void* l){
  __builtin_amdgcn_global_load_lds((const __attribute__((address_space(1))) unsigned int*)g,
                                   (__attribute__((address_space(3))) unsigned int*)l,
                                   16, 0, 0);
}

// ---------------- dtype detection ----------------
__global__ void detect_dtype(const u16* __restrict__ h, int* __restrict__ flag){
  int cnt = 0;
  for (int i = threadIdx.x; i < 256; i += 64) {
    float v = bf2f(h[2*i]);
    float a = fabsf(v);
    if (a >= 1e-12f && a <= 16.0f) cnt++;
  }
  #pragma unroll
  for (int o = 32; o; o >>= 1) cnt += __shfl_down(cnt, o);
  if (threadIdx.x == 0) *flag = (cnt >= 160) ? 1 : 0;
}

__global__ void sentinel_kernel(float* out){ out[0] = 12345.0f; }

// ---------------- convert to canonical bf16 ----------------
__global__ void to_bf16(const void* __restrict__ src, u16* __restrict__ dst,
                        int n8, const int* __restrict__ flag)
{
  int i = blockIdx.x * blockDim.x + threadIdx.x;
  if (i >= n8) return;
  if (*flag != 0) {
    ((uint4*)dst)[i] = ((const uint4*)src)[i];
  } else {
    const float4* s = (const float4*)src;
    float4 a = s[2*i], b = s[2*i+1];
    uint4 u;
    u.x = (unsigned)f2bf(a.x) | ((unsigned)f2bf(a.y) << 16);
    u.y = (unsigned)f2bf(a.z) | ((unsigned)f2bf(a.w) << 16);
    u.z = (unsigned)f2bf(b.x) | ((unsigned)f2bf(b.y) << 16);
    u.w = (unsigned)f2bf(b.z) | ((unsigned)f2bf(b.w) << 16);
    ((uint4*)dst)[i] = u;
  }
}

// ---------------- GEMM: C[M,N] = A[M,K] * B[N,K]^T (NT), bf16 in, fp32 acc ----
__global__ __launch_bounds__(256) void gemm_bt(const u16* __restrict__ A,
    const u16* __restrict__ B, void* __restrict__ C,
    int M, int N, int K, int out_mode, const int* __restrict__ flag)
{
  __shared__ u16 As[128*64];
  __shared__ u16 Bs[128*64];
  const int tid  = threadIdx.x;
  const int wave = tid >> 6;
  const int lane = tid & 63;
  const int quad = lane >> 4;
  const int l16  = lane & 15;
  const int wr = wave >> 1, wc = wave & 1;
  const int bm = blockIdx.y * 128;
  const int bn = blockIdx.x * 128;
  const int rsub = lane >> 3;
  const int csub = lane & 7;

  floatx4 acc[4][4];
  #pragma unroll
  for (int i = 0; i < 4; i++)
    #pragma unroll
    for (int j = 0; j < 4; j++)
      #pragma unroll
      for (int r = 0; r < 4; r++) acc[i][j][r] = 0.0f;

  for (int k0 = 0; k0 < K; k0 += 64) {
    #pragma unroll
    for (int i = 0; i < 4; i++) {
      const int s = wave*4 + i;
      const int r = s*8 + rsub;
      const int c = csub ^ (r & 7);
      const size_t goff = (size_t)r * K + (size_t)(k0 + c*8);
      async16(A + (size_t)bm * K + goff, &As[s*512]);
      async16(B + (size_t)bn * K + goff, &Bs[s*512]);
    }
    __syncthreads();
    #pragma unroll
    for (int ks = 0; ks < 2; ks++) {
      short8 fa[4], fb[4];
      #pragma unroll
      for (int mi = 0; mi < 4; mi++) {
        int m = wr*64 + mi*16 + l16;
        int phys = (ks*4 + quad) ^ (m & 7);
        fa[mi] = *(const short8*)&As[m*64 + phys*8];
      }
      #pragma unroll
      for (int ni = 0; ni < 4; ni++) {
        int n = wc*64 + ni*16 + l16;
        int phys = (ks*4 + quad) ^ (n & 7);
        fb[ni] = *(const short8*)&Bs[n*64 + phys*8];
      }
      #pragma unroll
      for (int mi = 0; mi < 4; mi++)
        #pragma unroll
        for (int ni = 0; ni < 4; ni++)
          acc[mi][ni] = __builtin_amdgcn_mfma_f32_16x16x32_bf16(fa[mi], fb[ni], acc[mi][ni], 0, 0, 0);
    }
    __syncthreads();
  }

  const bool outbf = (out_mode == 0) || (*flag != 0);
  #pragma unroll
  for (int mi = 0; mi < 4; mi++) {
    #pragma unroll
    for (int ni = 0; ni < 4; ni++) {
      #pragma unroll
      for (int r = 0; r < 4; r++) {
        int row = bm + wr*64 + mi*16 + quad*4 + r;
        int col = bn + wc*64 + ni*16 + l16;
        float v = acc[mi][ni][r];
        size_t idx = (size_t)row * N + col;
        if (outbf) ((u16*)C)[idx] = f2bf(v);
        else       ((float*)C)[idx] = v;
      }
    }
  }
}

// ---------------- RoPE in place; Q additionally scaled by 1/sqrt(HD) --------
__global__ void rope_kernel(u16* __restrict__ Q, u16* __restrict__ Kb,
                            const int* __restrict__ pos)
{
  int n = blockIdx.x * blockDim.x + threadIdx.x;  // S*NH*64
  if (n >= S_LEN * NH * 64) return;
  int s   = n >> 11;
  int rem = n & 2047;
  int h = rem >> 6;
  int j = rem & 63;
  float p = (float)pos[s];
  float inv = expf(-(float)j * 0.14391156831212787f);  // ln(10000)/64
  float arg = p * inv;
  float c = cosf(arg), sn = sinf(arg);
  const float SC = 0.08838834764831845f;  // 1/sqrt(128), folded into Q
  size_t base = (size_t)s * HID + (size_t)h * HD + j;
  float q1 = bf2f(Q[base]), q2 = bf2f(Q[base + 64]);
  Q[base]      = f2bf((q1 * c - q2 * sn) * SC);
  Q[base + 64] = f2bf((q2 * c + q1 * sn) * SC);
  float k1 = bf2f(Kb[base]), k2 = bf2f(Kb[base + 64]);
  Kb[base]      = f2bf(k1 * c - k2 * sn);
  Kb[base + 64] = f2bf(k2 * c + k1 * sn);
}

// ---------------- attention: one block per (head, 16-row q-tile) ------------
// 512 threads (8 waves). Dynamic LDS layout (bytes):
//   [0,131072)        float sc[16][2048]       scores
//   [131072,147456)   u32 hist[16][256]  ===  float wgt[16][256] (reused)
//   [147456,155648)   u16 idx[16][256]
//   [155648,156160)   per-row stats: dig[16], r[16], ceq[16], cnt[16]
#define ATTN_LDS 156160
__global__ __launch_bounds__(512) void attn_kernel(const u16* __restrict__ Q,
    const u16* __restrict__ Kb, const u16* __restrict__ V, u16* __restrict__ O)
{
  extern __shared__ char smem[];
  float*    sc     = (float*)smem;
  unsigned* hist   = (unsigned*)(smem + 131072);
  float*    wgt    = (float*)(smem + 131072);
  u16*      idxl   = (u16*)(smem + 147456);
  unsigned* st_dig = (unsigned*)(smem + 155648);
  unsigned* st_r   = st_dig + 16;
  unsigned* st_ceq = st_dig + 32;
  unsigned* st_cnt = st_dig + 48;

  const int tid  = threadIdx.x;
  const int q0   = blockIdx.x * 16;
  const int h    = blockIdx.y;
  const size_t hoff = (size_t)h * HD;

  // ---- Phase 1: scores via MFMA, direct global->register frags ----
  {
    const int wave = tid >> 6, lane = tid & 63;
    const int quad = lane >> 4, l16 = lane & 15;
    short8 afr[4];
    const u16* qrow = Q + (size_t)(q0 + l16) * HID + hoff;
    #pragma unroll
    for (int ks = 0; ks < 4; ks++)
      afr[ks] = *(const short8*)(qrow + ks*32 + quad*8);

    const int ntile = (q0 >> 4) + 1;
    for (int jt = wave; jt < ntile; jt += 8) {
      const u16* krow = Kb + (size_t)(jt*16 + l16) * HID + hoff;
      floatx4 c = {0.f, 0.f, 0.f, 0.f};
      #pragma unroll
      for (int ks = 0; ks < 4; ks++) {
        short8 bfr = *(const short8*)(krow + ks*32 + quad*8);
        c = __builtin_amdgcn_mfma_f32_16x16x32_bf16(afr[ks], bfr, c, 0, 0, 0);
      }
      const int j = jt*16 + l16;
      #pragma unroll
      for (int r = 0; r < 4; r++) {
        const int qq = quad*4 + r;           // C/D: row = quad*4+reg, col = lane&15
        sc[qq*2048 + j] = (j <= q0 + qq) ? c[r] : -INFINITY;
      }
    }
  }
  __syncthreads();

  // ---- Phase 2: per-row exact top-256 (4-pass radix select), 32 thr/row ----
  const int row = tid >> 5, t = tid & 31;
  const int q = q0 + row;
  const int valid = q + 1;
  const bool dosel = (valid > KSEL);
  float* scr = sc + row*2048;

  unsigned prefix = 0, rneed = KSEL;
  for (int shift = 24; shift >= 0; shift -= 8) {
    #pragma unroll
    for (int b = t; b < 256; b += 32) hist[row*256 + b] = 0u;
    __syncthreads();
    if (dosel) {
      for (int j = t; j <= q; j += 32) {
        unsigned k = okey(scr[j]);
        if (shift == 24 || (k >> (shift + 8)) == prefix)
          atomicAdd(&hist[row*256 + ((k >> shift) & 255)], 1u);
      }
    }
    __syncthreads();
    if (t == 0 && dosel) {
      unsigned a = 0;
      for (int dd = 255; dd >= 0; --dd) {
        unsigned cc = hist[row*256 + dd];
        if (a + cc >= rneed) { st_dig[row] = (unsigned)dd; st_r[row] = rneed - a; st_ceq[row] = cc; break; }
        a += cc;
      }
    }
    __syncthreads();
    if (dosel) { prefix = (prefix << 8) | st_dig[row]; rneed = st_r[row]; }
  }
  const unsigned tkey = prefix;
  // tie fixup: keep lowest-index ties only (reference top_k semantics)
  if (t == 0 && dosel && st_ceq[row] != rneed) {
    unsigned seen = 0;
    for (int j = 0; j <= q; j++) {
      if (okey(scr[j]) == tkey) { if (seen >= rneed) scr[j] = -INFINITY; seen++; }
    }
  }
  if (t == 0) st_cnt[row] = 0u;
  __syncthreads();

  // ---- Phase 3: compact selected indices + row max ----
  float m = -INFINITY;
  for (int j = t; j <= q; j += 32) {
    float s = scr[j];
    bool sel = dosel ? (okey(s) >= tkey) : true;
    if (sel) {
      unsigned p = atomicAdd(&st_cnt[row], 1u);
      idxl[row*256 + p] = (u16)j;
      m = fmaxf(m, s);
    }
  }
  #pragma unroll
  for (int o = 16; o; o >>= 1) m = fmaxf(m, __shfl_down(m, o, 32));
  m = __shfl(m, 0, 32);
  __syncthreads();

  const int n = (int)st_cnt[row];
  float lsum = 0.f;
  for (int i = t; i < n; i += 32) {
    float w = __expf(scr[idxl[row*256 + i]] - m);
    wgt[row*256 + i] = w;            // hist region is dead now
    lsum += w;
  }
  #pragma unroll
  for (int o = 16; o; o >>= 1) lsum += __shfl_down(lsum, o, 32);
  lsum = __shfl(lsum, 0, 32);
  const float invs = 1.f / lsum;
  __syncthreads();

  // ---- Phase 4: PV over compacted list; 4 dims per thread ----
  const int d0 = t * 4;
  float a0 = 0.f, a1 = 0.f, a2 = 0.f, a3 = 0.f;
  for (int i = 0; i < n; i++) {
    const int j = idxl[row*256 + i];
    const float w = wgt[row*256 + i];
    uint2 p = *(const uint2*)(V + (size_t)j * HID + hoff + d0);
    a0 += w * __uint_as_float(p.x << 16);
    a1 += w * __uint_as_float(p.x & 0xffff0000u);
    a2 += w * __uint_as_float(p.y << 16);
    a3 += w * __uint_as_float(p.y & 0xffff0000u);
  }
  uint2 ov;
  ov.x = (unsigned)f2bf(a0 * invs) | ((unsigned)f2bf(a1 * invs) << 16);
  ov.y = (unsigned)f2bf(a2 * invs) | ((unsigned)f2bf(a3 * invs) << 16);
  *(uint2*)(O + (size_t)q * HID + hoff + d0) = ov;
}

// ---------------- launch ----------------
extern "C" void kernel_launch(void* const* d_in, const int* in_sizes, int n_in,
                              void* d_out, int out_size, void* d_ws, size_t ws_size,
                              hipStream_t stream)
{
  (void)in_sizes; (void)n_in; (void)out_size;
  const void* hidden = d_in[0];
  const int*  pos    = (const int*)d_in[2];
  const void* Wq     = d_in[3];
  const void* Wk     = d_in[4];
  const void* Wv     = d_in[5];
  const void* Wo     = d_in[6];

  const size_t SH2 = (size_t)S_LEN * HID * 2;
  const size_t W2  = (size_t)HID * HID * 2;
  const size_t NEEDED = 256 + SH2 + W2 + 3 * SH2 + SH2;
  if (ws_size < NEEDED) {
    sentinel_kernel<<<1, 1, 0, stream>>>((float*)d_out);
    return;
  }

  char* ws = (char*)d_ws;
  int* flag = (int*)ws;
  u16* hb = (u16*)(ws + 256);
  u16* wb = (u16*)(ws + 256 + SH2);
  u16* qb = (u16*)(ws + 256 + SH2 + W2);
  u16* kb = (u16*)(ws + 256 + SH2 + W2 + SH2);
  u16* vb = (u16*)(ws + 256 + SH2 + W2 + 2 * SH2);
  u16* ab = (u16*)(ws + 256 + SH2 + W2 + 3 * SH2);

  detect_dtype<<<1, 64, 0, stream>>>((const u16*)hidden, flag);

  const int nh8 = S_LEN * HID / 8;
  const int nw8 = HID * HID / 8;
  to_bf16<<<nh8 / 256, 256, 0, stream>>>(hidden, hb, nh8, flag);

  dim3 ggrid(HID / 128, S_LEN / 128);

  to_bf16<<<nw8 / 256, 256, 0, stream>>>(Wq, wb, nw8, flag);
  gemm_bt<<<ggrid, 256, 0, stream>>>(hb, wb, (void*)qb, S_LEN, HID, HID, 0, flag);

  to_bf16<<<nw8 / 256, 256, 0, stream>>>(Wk, wb, nw8, flag);
  gemm_bt<<<ggrid, 256, 0, stream>>>(hb, wb, (void*)kb, S_LEN, HID, HID, 0, flag);

  to_bf16<<<nw8 / 256, 256, 0, stream>>>(Wv, wb, nw8, flag);
  gemm_bt<<<ggrid, 256, 0, stream>>>(hb, wb, (void*)vb, S_LEN, HID, HID, 0, flag);

  rope_kernel<<<(S_LEN * NH * 64) / 256, 256, 0, stream>>>(qb, kb, pos);

  // defensive: allow >64KB dynamic LDS (no-op if not required on ROCm)
  (void)hipFuncSetAttribute(reinterpret_cast<const void*>(&attn_kernel),
                            hipFuncAttributeMaxDynamicSharedMemorySize, ATTN_LDS);
  attn_kernel<<<dim3(S_LEN / 16, NH), 512, ATTN_LDS, stream>>>(qb, kb, vb, ab);

  to_bf16<<<nw8 / 256, 256, 0, stream>>>(Wo, wb, nw8, flag);
  gemm_bt<<<ggrid, 256, 0, stream>>>(ab, wb, d_out, S_LEN, HID, HID, 1, flag);
}

// Round 3
// 2250.162 us; speedup vs baseline: 10.1636x; 1.0945x over previous
//
#include <hip/hip_runtime.h>
#include <stdint.h>
#include <math.h>

#define S_LEN 2048
#define HID   4096
#define NH    32
#define HD    128
#define KSEL  256

typedef unsigned short u16;
typedef unsigned long long u64;
typedef __attribute__((ext_vector_type(8))) short short8;
typedef __attribute__((ext_vector_type(4))) float floatx4;

__device__ __forceinline__ float bf2f(u16 u){ return __uint_as_float(((unsigned)u) << 16); }
__device__ __forceinline__ u16 f2bf(float f){
  unsigned u = __float_as_uint(f);
  u += 0x7fffu + ((u >> 16) & 1u);   // RTNE
  return (u16)(u >> 16);
}
// monotonic float -> unsigned key (larger float -> larger key)
__device__ __forceinline__ unsigned okey(float x){
  unsigned b = __float_as_uint(x);
  return (b & 0x80000000u) ? ~b : (b | 0x80000000u);
}
__device__ __forceinline__ float unokey(unsigned k){
  unsigned b = (k & 0x80000000u) ? (k & 0x7fffffffu) : ~k;
  return __uint_as_float(b);
}
__device__ __forceinline__ void async16(const void* g, void* l){
  __builtin_amdgcn_global_load_lds((const __attribute__((address_space(1))) unsigned int*)g,
                                   (__attribute__((address_space(3))) unsigned int*)l,
                                   16, 0, 0);
}

// ---------------- dtype detection ----------------
__global__ void detect_dtype(const u16* __restrict__ h, int* __restrict__ flag){
  int cnt = 0;
  for (int i = threadIdx.x; i < 256; i += 64) {
    float v = bf2f(h[2*i]);
    float a = fabsf(v);
    if (a >= 1e-12f && a <= 16.0f) cnt++;
  }
  #pragma unroll
  for (int o = 32; o; o >>= 1) cnt += __shfl_down(cnt, o);
  if (threadIdx.x == 0) *flag = (cnt >= 160) ? 1 : 0;
}

__global__ void sentinel_kernel(float* out){ out[0] = 12345.0f; }

// ---------------- convert to canonical bf16 ----------------
__global__ void to_bf16(const void* __restrict__ src, u16* __restrict__ dst,
                        int n8, const int* __restrict__ flag)
{
  int i = blockIdx.x * blockDim.x + threadIdx.x;
  if (i >= n8) return;
  if (*flag != 0) {
    ((uint4*)dst)[i] = ((const uint4*)src)[i];
  } else {
    const float4* s = (const float4*)src;
    float4 a = s[2*i], b = s[2*i+1];
    uint4 u;
    u.x = (unsigned)f2bf(a.x) | ((unsigned)f2bf(a.y) << 16);
    u.y = (unsigned)f2bf(a.z) | ((unsigned)f2bf(a.w) << 16);
    u.z = (unsigned)f2bf(b.x) | ((unsigned)f2bf(b.y) << 16);
    u.w = (unsigned)f2bf(b.z) | ((unsigned)f2bf(b.w) << 16);
    ((uint4*)dst)[i] = u;
  }
}

// ---------------- GEMM: C[M,N] = A[M,K] * B[N,K]^T (NT), bf16 in, fp32 acc ----
__global__ __launch_bounds__(256) void gemm_bt(const u16* __restrict__ A,
    const u16* __restrict__ B, void* __restrict__ C,
    int M, int N, int K, int out_mode, const int* __restrict__ flag)
{
  __shared__ u16 As[128*64];
  __shared__ u16 Bs[128*64];
  const int tid  = threadIdx.x;
  const int wave = tid >> 6;
  const int lane = tid & 63;
  const int quad = lane >> 4;
  const int l16  = lane & 15;
  const int wr = wave >> 1, wc = wave & 1;
  const int bm = blockIdx.y * 128;
  const int bn = blockIdx.x * 128;
  const int rsub = lane >> 3;
  const int csub = lane & 7;

  floatx4 acc[4][4];
  #pragma unroll
  for (int i = 0; i < 4; i++)
    #pragma unroll
    for (int j = 0; j < 4; j++)
      #pragma unroll
      for (int r = 0; r < 4; r++) acc[i][j][r] = 0.0f;

  for (int k0 = 0; k0 < K; k0 += 64) {
    #pragma unroll
    for (int i = 0; i < 4; i++) {
      const int s = wave*4 + i;
      const int r = s*8 + rsub;
      const int c = csub ^ (r & 7);
      const size_t goff = (size_t)r * K + (size_t)(k0 + c*8);
      async16(A + (size_t)bm * K + goff, &As[s*512]);
      async16(B + (size_t)bn * K + goff, &Bs[s*512]);
    }
    __syncthreads();
    #pragma unroll
    for (int ks = 0; ks < 2; ks++) {
      short8 fa[4], fb[4];
      #pragma unroll
      for (int mi = 0; mi < 4; mi++) {
        int m = wr*64 + mi*16 + l16;
        int phys = (ks*4 + quad) ^ (m & 7);
        fa[mi] = *(const short8*)&As[m*64 + phys*8];
      }
      #pragma unroll
      for (int ni = 0; ni < 4; ni++) {
        int n = wc*64 + ni*16 + l16;
        int phys = (ks*4 + quad) ^ (n & 7);
        fb[ni] = *(const short8*)&Bs[n*64 + phys*8];
      }
      #pragma unroll
      for (int mi = 0; mi < 4; mi++)
        #pragma unroll
        for (int ni = 0; ni < 4; ni++)
          acc[mi][ni] = __builtin_amdgcn_mfma_f32_16x16x32_bf16(fa[mi], fb[ni], acc[mi][ni], 0, 0, 0);
    }
    __syncthreads();
  }

  const bool outbf = (out_mode == 0) || (*flag != 0);
  #pragma unroll
  for (int mi = 0; mi < 4; mi++) {
    #pragma unroll
    for (int ni = 0; ni < 4; ni++) {
      #pragma unroll
      for (int r = 0; r < 4; r++) {
        int row = bm + wr*64 + mi*16 + quad*4 + r;
        int col = bn + wc*64 + ni*16 + l16;
        float v = acc[mi][ni][r];
        size_t idx = (size_t)row * N + col;
        if (outbf) ((u16*)C)[idx] = f2bf(v);
        else       ((float*)C)[idx] = v;
      }
    }
  }
}

// ---------------- RoPE in place; Q additionally scaled by 1/sqrt(HD) --------
__global__ void rope_kernel(u16* __restrict__ Q, u16* __restrict__ Kb,
                            const int* __restrict__ pos)
{
  int n = blockIdx.x * blockDim.x + threadIdx.x;  // S*NH*64
  if (n >= S_LEN * NH * 64) return;
  int s   = n >> 11;
  int rem = n & 2047;
  int h = rem >> 6;
  int j = rem & 63;
  float p = (float)pos[s];
  float inv = expf(-(float)j * 0.14391156831212787f);  // ln(10000)/64
  float arg = p * inv;
  float c = cosf(arg), sn = sinf(arg);
  const float SC = 0.08838834764831845f;  // 1/sqrt(128), folded into Q
  size_t base = (size_t)s * HID + (size_t)h * HD + j;
  float q1 = bf2f(Q[base]), q2 = bf2f(Q[base + 64]);
  Q[base]      = f2bf((q1 * c - q2 * sn) * SC);
  Q[base + 64] = f2bf((q2 * c + q1 * sn) * SC);
  float k1 = bf2f(Kb[base]), k2 = bf2f(Kb[base + 64]);
  Kb[base]      = f2bf(k1 * c - k2 * sn);
  Kb[base + 64] = f2bf(k2 * c + k1 * sn);
}

// ---------------- attention: one block per (head, 16-row q-tile) ------------
// 512 threads (8 waves). Scores live in REGISTERS (16 floatx4 per thread).
// Selection: radix-select on 48-bit composite key (okey(s)<<16)|((2047-j)<<5)
//   -> unique keys, exactly KSEL selected, no tie fixup. Passes 5-6 (index
//   bits) only run if a boundary tie exists after the 4 okey passes.
// LDS (41,472 B): hist u32[16][256] | sel f32[16][256] (score->weight) |
//                 idx u16[16][256] | state 512B
#define ATTN_LDS (16384 + 16384 + 8192 + 512)
__global__ __launch_bounds__(512, 4) void attn_kernel(const u16* __restrict__ Q,
    const u16* __restrict__ Kb, const u16* __restrict__ V, u16* __restrict__ O)
{
  extern __shared__ char smem[];
  unsigned* hist  = (unsigned*)smem;                  // [16][256]
  float*    sel   = (float*)(smem + 16384);           // [16][256]
  u16*      idxl  = (u16*)(smem + 32768);             // [16][256]
  char*     stb   = smem + 40960;
  u64*      pref  = (u64*)stb;                        // [16]
  unsigned* rneedA= (unsigned*)(stb + 128);           // [16]
  unsigned* shA   = (unsigned*)(stb + 192);           // [16]
  unsigned* doneA = (unsigned*)(stb + 256);           // [16]
  unsigned* cntA  = (unsigned*)(stb + 320);           // [16]
  unsigned* umaxA = (unsigned*)(stb + 384);           // [16]
  unsigned* flagT = (unsigned*)(stb + 448);           // [1]

  const int tid  = threadIdx.x;
  const int wave = tid >> 6, lane = tid & 63;
  const int quad = lane >> 4, l16 = lane & 15;
  const int quad4 = quad * 4;
  const int qt   = (S_LEN/16 - 1) - blockIdx.x;   // heavy tiles first
  const int q0   = qt * 16;
  const int h    = blockIdx.y;
  const size_t hoff = (size_t)h * HD;
  const int ntile = qt + 1;

  // state init (LDS untouched by phase 1 otherwise)
  if (tid < 16) {
    pref[tid]  = 0ull;
    rneedA[tid]= KSEL;
    doneA[tid] = ((q0 + tid + 1) > KSEL) ? 0u : 1u;  // !dosel rows skip passes
    cntA[tid]  = 0u;
    umaxA[tid] = 0u;
    shA[tid]   = 0u;
  }
  if (tid == 0) flagT[0] = 0u;

  // ---- Phase 1: scores via MFMA, K streamed from global, acc in registers --
  floatx4 c[16];
  {
    short8 afr[4];
    const u16* qrow = Q + (size_t)(q0 + l16) * HID + hoff;
    #pragma unroll
    for (int ks = 0; ks < 4; ks++)
      afr[ks] = *(const short8*)(qrow + ks*32 + quad*8);

    for (int i = 0; i < 16; i++) {
      int jt = wave + 8*i;
      if (jt >= ntile) break;
      const u16* krow = Kb + (size_t)(jt*16 + l16) * HID + hoff;
      floatx4 acc = {0.f, 0.f, 0.f, 0.f};
      #pragma unroll
      for (int ks = 0; ks < 4; ks++) {
        short8 bfr = *(const short8*)(krow + ks*32 + quad*8);
        acc = __builtin_amdgcn_mfma_f32_16x16x32_bf16(afr[ks], bfr, acc, 0, 0, 0);
      }
      c[i] = acc;   // rows quad4..quad4+3, col j = jt*16 + l16
    }
  }
  __syncthreads();

  // ---- Phase 2: radix select over register scores ----
  const int srow = tid >> 5;       // row owned by this half-wave for scans
  const int t    = tid & 31;

  for (int p = 0; p < 6; p++) {
    const int sh = 40 - 8*p;
    if (p >= 4 && flagT[0] == 0u) break;   // uniform: no boundary ties anywhere
    // zero histograms
    #pragma unroll
    for (int b = 0; b < 8; b++) hist[tid + b*512] = 0u;
    __syncthreads();
    // accumulate
    {
      unsigned myDone[4]; u64 myPref[4];
      #pragma unroll
      for (int r = 0; r < 4; r++) { myDone[r] = doneA[quad4+r]; myPref[r] = pref[quad4+r]; }
      for (int i = 0; i < 16; i++) {
        int jt = wave + 8*i;
        if (jt >= ntile) break;
        int j = jt*16 + l16;
        #pragma unroll
        for (int r = 0; r < 4; r++) {
          if (myDone[r]) continue;
          int row = quad4 + r;
          if (j > q0 + row) continue;
          u64 ek = ((u64)okey(c[i][r]) << 16) | (unsigned)((2047 - j) << 5);
          if ((ek >> (sh + 8)) == myPref[r])
            atomicAdd(&hist[row*256 + (unsigned)((ek >> sh) & 255u)], 1u);
        }
      }
    }
    __syncthreads();
    // digit scan: half-wave per row, 8 bins per lane, suffix order
    if (doneA[srow] == 0u) {
      unsigned hv[8], part = 0;
      const int baseb = srow*256 + 248 - 8*t;
      #pragma unroll
      for (int k2 = 0; k2 < 8; k2++) { hv[k2] = hist[baseb + k2]; part += hv[k2]; }
      unsigned pre = part;
      #pragma unroll
      for (int o = 1; o < 32; o <<= 1) { unsigned v2 = __shfl_up(pre, o, 32); if (t >= o) pre += v2; }
      pre -= part;   // count of keys in strictly higher chunks
      unsigned rn = rneedA[srow];
      if (pre < rn && pre + part >= rn) {     // unique finder lane
        unsigned a = pre;
        #pragma unroll
        for (int k2 = 7; k2 >= 0; k2--) {
          unsigned cc = hv[k2];
          if (a + cc >= rn) {
            unsigned dig = (unsigned)(248 - 8*t + k2);
            pref[srow] = (pref[srow] << 8) | dig;
            unsigned newr = rn - a;
            rneedA[srow] = newr;
            if (cc == newr) { doneA[srow] = 1u; shA[srow] = (unsigned)sh; }
            else if (sh == 16) flagT[0] = 1u;   // need index passes
            break;
          }
          a += cc;
        }
      }
    }
    __syncthreads();
  }

  // ---- Phase 3: compaction (exactly min(valid,KSEL) per row) + row max ----
  {
    u64 myT[4]; unsigned mySh[4]; bool myDs[4];
    #pragma unroll
    for (int r = 0; r < 4; r++) {
      int rr = quad4 + r;
      myT[r] = pref[rr]; mySh[r] = shA[rr];
      myDs[r] = (q0 + rr + 1) > KSEL;
    }
    for (int i = 0; i < 16; i++) {
      int jt = wave + 8*i;
      if (jt >= ntile) break;
      int j = jt*16 + l16;
      #pragma unroll
      for (int r = 0; r < 4; r++) {
        int row = quad4 + r;
        if (j > q0 + row) continue;
        float s = c[i][r];
        bool keep;
        if (!myDs[r]) keep = true;
        else {
          u64 ek = ((u64)okey(s) << 16) | (unsigned)((2047 - j) << 5);
          keep = (ek >> mySh[r]) >= myT[r];
        }
        if (keep) {
          unsigned pos = atomicAdd(&cntA[row], 1u);
          idxl[row*256 + pos] = (u16)j;
          sel[row*256 + pos]  = s;
          atomicMax(&umaxA[row], okey(s));
        }
      }
    }
  }
  __syncthreads();

  // ---- Phase 4: softmax weights per row (half-wave) ----
  const int n = (int)cntA[srow];
  {
    const float m = unokey(umaxA[srow]);
    float lsum = 0.f;
    for (int i = t; i < n; i += 32) {
      float w = __expf(sel[srow*256 + i] - m);
      sel[srow*256 + i] = w;
      lsum += w;
    }
    #pragma unroll
    for (int o = 16; o; o >>= 1) lsum += __shfl_down(lsum, o, 32);
    lsum = __shfl(lsum, 0, 32);
    umaxA[srow] = __float_as_uint(1.f / lsum);  // stash invs (safe: umax dead)
  }
  __syncthreads();

  // ---- Phase 5: PV over compacted list; half-wave per row, 4 dims/lane ----
  {
    const float invs = __uint_as_float(umaxA[srow]);
    const int d0 = t * 4;
    float a0 = 0.f, a1 = 0.f, a2 = 0.f, a3 = 0.f;
    int i = 0;
    for (; i + 4 <= n; i += 4) {
      int   j0 = idxl[srow*256+i+0], j1 = idxl[srow*256+i+1],
            j2 = idxl[srow*256+i+2], j3 = idxl[srow*256+i+3];
      float w0 = sel[srow*256+i+0], w1 = sel[srow*256+i+1],
            w2 = sel[srow*256+i+2], w3 = sel[srow*256+i+3];
      uint2 p0 = *(const uint2*)(V + (size_t)j0 * HID + hoff + d0);
      uint2 p1 = *(const uint2*)(V + (size_t)j1 * HID + hoff + d0);
      uint2 p2 = *(const uint2*)(V + (size_t)j2 * HID + hoff + d0);
      uint2 p3 = *(const uint2*)(V + (size_t)j3 * HID + hoff + d0);
      a0 += w0*__uint_as_float(p0.x<<16) + w1*__uint_as_float(p1.x<<16)
          + w2*__uint_as_float(p2.x<<16) + w3*__uint_as_float(p3.x<<16);
      a1 += w0*__uint_as_float(p0.x&0xffff0000u) + w1*__uint_as_float(p1.x&0xffff0000u)
          + w2*__uint_as_float(p2.x&0xffff0000u) + w3*__uint_as_float(p3.x&0xffff0000u);
      a2 += w0*__uint_as_float(p0.y<<16) + w1*__uint_as_float(p1.y<<16)
          + w2*__uint_as_float(p2.y<<16) + w3*__uint_as_float(p3.y<<16);
      a3 += w0*__uint_as_float(p0.y&0xffff0000u) + w1*__uint_as_float(p1.y&0xffff0000u)
          + w2*__uint_as_float(p2.y&0xffff0000u) + w3*__uint_as_float(p3.y&0xffff0000u);
    }
    for (; i < n; i++) {
      int j = idxl[srow*256+i]; float w = sel[srow*256+i];
      uint2 p = *(const uint2*)(V + (size_t)j * HID + hoff + d0);
      a0 += w*__uint_as_float(p.x<<16);  a1 += w*__uint_as_float(p.x&0xffff0000u);
      a2 += w*__uint_as_float(p.y<<16);  a3 += w*__uint_as_float(p.y&0xffff0000u);
    }
    uint2 ov;
    ov.x = (unsigned)f2bf(a0*invs) | ((unsigned)f2bf(a1*invs) << 16);
    ov.y = (unsigned)f2bf(a2*invs) | ((unsigned)f2bf(a3*invs) << 16);
    *(uint2*)(O + (size_t)(q0 + srow) * HID + hoff + d0) = ov;
  }
}

// ---------------- launch ----------------
extern "C" void kernel_launch(void* const* d_in, const int* in_sizes, int n_in,
                              void* d_out, int out_size, void* d_ws, size_t ws_size,
                              hipStream_t stream)
{
  (void)in_sizes; (void)n_in; (void)out_size;
  const void* hidden = d_in[0];
  const int*  pos    = (const int*)d_in[2];
  const void* Wq     = d_in[3];
  const void* Wk     = d_in[4];
  const void* Wv     = d_in[5];
  const void* Wo     = d_in[6];

  const size_t SH2 = (size_t)S_LEN * HID * 2;
  const size_t W2  = (size_t)HID * HID * 2;
  const size_t NEEDED = 256 + SH2 + W2 + 3 * SH2 + SH2;
  if (ws_size < NEEDED) {
    sentinel_kernel<<<1, 1, 0, stream>>>((float*)d_out);
    return;
  }

  char* ws = (char*)d_ws;
  int* flag = (int*)ws;
  u16* hb = (u16*)(ws + 256);
  u16* wb = (u16*)(ws + 256 + SH2);
  u16* qb = (u16*)(ws + 256 + SH2 + W2);
  u16* kb = (u16*)(ws + 256 + SH2 + W2 + SH2);
  u16* vb = (u16*)(ws + 256 + SH2 + W2 + 2 * SH2);
  u16* ab = (u16*)(ws + 256 + SH2 + W2 + 3 * SH2);

  detect_dtype<<<1, 64, 0, stream>>>((const u16*)hidden, flag);

  const int nh8 = S_LEN * HID / 8;
  const int nw8 = HID * HID / 8;
  to_bf16<<<nh8 / 256, 256, 0, stream>>>(hidden, hb, nh8, flag);

  dim3 ggrid(HID / 128, S_LEN / 128);

  to_bf16<<<nw8 / 256, 256, 0, stream>>>(Wq, wb, nw8, flag);
  gemm_bt<<<ggrid, 256, 0, stream>>>(hb, wb, (void*)qb, S_LEN, HID, HID, 0, flag);

  to_bf16<<<nw8 / 256, 256, 0, stream>>>(Wk, wb, nw8, flag);
  gemm_bt<<<ggrid, 256, 0, stream>>>(hb, wb, (void*)kb, S_LEN, HID, HID, 0, flag);

  to_bf16<<<nw8 / 256, 256, 0, stream>>>(Wv, wb, nw8, flag);
  gemm_bt<<<ggrid, 256, 0, stream>>>(hb, wb, (void*)vb, S_LEN, HID, HID, 0, flag);

  rope_kernel<<<(S_LEN * NH * 64) / 256, 256, 0, stream>>>(qb, kb, pos);

  attn_kernel<<<dim3(S_LEN / 16, NH), 512, ATTN_LDS, stream>>>(qb, kb, vb, ab);

  to_bf16<<<nw8 / 256, 256, 0, stream>>>(Wo, wb, nw8, flag);
  gemm_bt<<<ggrid, 256, 0, stream>>>(ab, wb, d_out, S_LEN, HID, HID, 1, flag);
}